// Round 3
// baseline (1622.084 us; speedup 1.0000x reference)
//
#include <hip/hip_runtime.h>
#include <cmath>

#define SOS 0
#define EOS 1
#define Bb 128
#define Ss 1024
#define Tt 128
#define LOG2E 1.4426950408889634f
#define LN2f  0.6931471805599453f

typedef float f32x2 __attribute__((ext_vector_type(2)));
typedef float f32x4 __attribute__((ext_vector_type(4)));

// packed fp32 FMA: acc.{x,y} += a.{x,y} * b.{x,y}  (CDNA full-rate packed math)
__device__ __forceinline__ void pkfma(f32x2& acc, f32x2 a, f32x2 b) {
  asm("v_pk_fma_f32 %0, %1, %2, %0" : "+v"(acc) : "v"(a), "v"(b));
}

// ---------------------------------------------------------------------------
// One step of the linear-space recurrence. Single wave, no barriers.
// Lane l owns output columns j0=2l, j0+1. exp(trans) register-resident
// (MA/MB: k-paired packed columns). f published through LDS (broadcast reads).
// PH: phase in the 4-step rescale cycle (measure at PH==3, apply at PH==0).
// ---------------------------------------------------------------------------
template<int PH>
__device__ __forceinline__ void crf_step(
    int i, const float* __restrict__ em, size_t base, int j0,
    float* s_f, const float* s_mask,
    const f32x2 (&MA)[64], const f32x2 (&MB)[64],
    f32x2& fprev, f32x2& pf, float& c_scale, float& nxt_scl, float& nxt_e)
{
  // publish f_{i-1} (in-wave DS ordering makes this visible to the reads)
  *(f32x2*)&s_f[j0] = fprev;
  float mi = s_mask[i];
  f32x2 emv = pf;
  // refill this phase's prefetch slot with row i+4 (true 4-step distance)
  int r = (i + 4 < Ss) ? (i + 4) : (Ss - 1);
  pf = *(const f32x2*)&em[base + (size_t)r * Tt + j0];

  float sclv = 1.0f;
  if constexpr (PH == 0) { sclv = nxt_scl; c_scale += nxt_e; }

  // 128-deep dot for both columns: 128 pk_fma, 4 chains of 32
  f32x2 aA0 = {0.f, 0.f}, aA1 = {0.f, 0.f};
  f32x2 aB0 = {0.f, 0.f}, aB1 = {0.f, 0.f};
  const f32x4* fq = (const f32x4*)s_f;
  #pragma unroll
  for (int q = 0; q < 32; ++q) {
    f32x4 v = fq[q];                                   // uniform addr: broadcast
    f32x2 lo = __builtin_shufflevector(v, v, 0, 1);
    f32x2 hi = __builtin_shufflevector(v, v, 2, 3);
    pkfma(aA0, lo, MA[2 * q]);
    pkfma(aA1, hi, MA[2 * q + 1]);
    pkfma(aB0, lo, MB[2 * q]);
    pkfma(aB1, hi, MB[2 * q + 1]);
  }
  f32x2 g;
  g.x = (aA0.x + aA0.y) + (aA1.x + aA1.y);
  g.y = (aB0.x + aB0.y) + (aB1.x + aB1.y);

  f32x2 fn;
  fn.x = g.x * (exp2f(emv.x * LOG2E) * sclv);
  fn.y = g.y * (exp2f(emv.y * LOG2E) * sclv);
  if (mi == 0.f) { fn.x = fprev.x * sclv; fn.y = fprev.y * sclv; }
  fprev = fn;

  if constexpr (PH == 3) {   // measure max for the rescale applied at PH==0
    float v = fmaxf(fn.x, fn.y);
    #pragma unroll
    for (int o = 32; o > 0; o >>= 1) v = fmaxf(v, __shfl_xor(v, o));
    int e2; (void)frexpf(v, &e2);                  // v = m*2^e2, m in [0.5,1)
    nxt_scl = __int_as_float((127 - e2) << 23);    // 2^-e2
    nxt_e = (float)e2;
  }
}

// ---------------------------------------------------------------------------
// Forward (partition): one block = ONE wave per batch element.
// ---------------------------------------------------------------------------
__global__ __launch_bounds__(64, 1) void crf_forward(
    const float* __restrict__ em, const float* __restrict__ trans,
    const float* __restrict__ mask, float* __restrict__ part_out)
{
  __shared__ __align__(16) float s_f[Tt];
  __shared__ __align__(16) float s_mask[Ss];

  const int l = threadIdx.x;       // 0..63
  const int j0 = 2 * l;
  const int b = blockIdx.x;
  const size_t base = (size_t)b * Ss * Tt;

  for (int i = l; i < Ss; i += 64) s_mask[i] = mask[b * Ss + i];

  // register-resident exp2(trans*log2e), k-paired for packed math:
  // MA[k2] = (M[2k2][j0],   M[2k2+1][j0]),  MB same for column j0+1
  f32x2 MA[64], MB[64];
  #pragma unroll
  for (int k2 = 0; k2 < 64; ++k2) {
    f32x2 r0 = *(const f32x2*)&trans[(2 * k2 + 0) * Tt + j0];
    f32x2 r1 = *(const f32x2*)&trans[(2 * k2 + 1) * Tt + j0];
    MA[k2] = f32x2{ exp2f(r0.x * LOG2E), exp2f(r1.x * LOG2E) };
    MB[k2] = f32x2{ exp2f(r0.y * LOG2E), exp2f(r1.y * LOG2E) };
  }
  const f32x2 tS = *(const f32x2*)&trans[SOS * Tt + j0];
  const float eA = exp2f(trans[(j0 + 0) * Tt + EOS] * LOG2E);
  const float eB = exp2f(trans[(j0 + 1) * Tt + EOS] * LOG2E);

  // init: f0 = exp(trans[SOS,j] + em[b,0,j])
  f32x2 e0 = *(const f32x2*)&em[base + j0];
  f32x2 fprev;
  fprev.x = exp2f((tS.x + e0.x) * LOG2E);
  fprev.y = exp2f((tS.y + e0.y) * LOG2E);

  // prime 4 prefetch slots: row i consumed by phase i&3
  f32x2 pf1 = *(const f32x2*)&em[base + (size_t)1 * Tt + j0];
  f32x2 pf2 = *(const f32x2*)&em[base + (size_t)2 * Tt + j0];
  f32x2 pf3 = *(const f32x2*)&em[base + (size_t)3 * Tt + j0];
  f32x2 pf0 = *(const f32x2*)&em[base + (size_t)4 * Tt + j0];

  float c_scale = 0.f, nxt_scl = 1.f, nxt_e = 0.f;
  __syncthreads();   // one-time: mask staging (single wave, near-free)

  int i = 1;
  for (; i + 3 < Ss; i += 4) {
    crf_step<1>(i + 0, em, base, j0, s_f, s_mask, MA, MB, fprev, pf1, c_scale, nxt_scl, nxt_e);
    crf_step<2>(i + 1, em, base, j0, s_f, s_mask, MA, MB, fprev, pf2, c_scale, nxt_scl, nxt_e);
    crf_step<3>(i + 2, em, base, j0, s_f, s_mask, MA, MB, fprev, pf3, c_scale, nxt_scl, nxt_e);
    crf_step<0>(i + 3, em, base, j0, s_f, s_mask, MA, MB, fprev, pf0, c_scale, nxt_scl, nxt_e);
  }
  // tail: i = 1021, 1022, 1023 (phases 1,2,3)
  crf_step<1>(i + 0, em, base, j0, s_f, s_mask, MA, MB, fprev, pf1, c_scale, nxt_scl, nxt_e);
  crf_step<2>(i + 1, em, base, j0, s_f, s_mask, MA, MB, fprev, pf2, c_scale, nxt_scl, nxt_e);
  crf_step<3>(i + 2, em, base, j0, s_f, s_mask, MA, MB, fprev, pf3, c_scale, nxt_scl, nxt_e);

  // partition = ln( sum_j f[j]*exp(trans[j,EOS]) ) + c*ln2
  float v = fprev.x * eA + fprev.y * eB;
  #pragma unroll
  for (int o = 32; o > 0; o >>= 1) v += __shfl_xor(v, o);
  if (l == 0) part_out[b] = (log2f(v) + c_scale) * LN2f;
}

// ---------------------------------------------------------------------------
// Score (numerator) kernel: one block per batch element, gather + reduce.
// ---------------------------------------------------------------------------
__global__ __launch_bounds__(256) void crf_score(
    const float* __restrict__ em, const float* __restrict__ trans,
    const float* __restrict__ mask, const int* __restrict__ tags,
    float* __restrict__ sc)
{
  __shared__ float s_red[4];
  __shared__ float s_red2[4];
  const int tid = threadIdx.x;
  const int b = blockIdx.x;
  const size_t em_base = (size_t)b * Ss * Tt;
  const int* tg = tags + b * Ss;
  const float* mk = mask + b * Ss;

  float part = 0.f, msum = 0.f;
  for (int i = tid; i < Ss; i += 256) {
    float m = mk[i];
    msum += m;
    if (i >= 1) {
      int tc = tg[i], tp = tg[i - 1];
      part += m * (em[em_base + (size_t)i * Tt + tc] + trans[tp * Tt + tc]);
    }
  }
  #pragma unroll
  for (int o = 32; o > 0; o >>= 1) {
    part += __shfl_xor(part, o);
    msum += __shfl_xor(msum, o);
  }
  if ((tid & 63) == 0) { s_red[tid >> 6] = part; s_red2[tid >> 6] = msum; }
  __syncthreads();
  if (tid == 0) {
    float p  = s_red[0] + s_red[1] + s_red[2] + s_red[3];
    float ms = s_red2[0] + s_red2[1] + s_red2[2] + s_red2[3];
    int last = (int)(ms + 0.5f) - 1;
    int t0 = tg[0];
    float s = trans[SOS * Tt + t0] + em[em_base + t0] + p
            + trans[tg[last] * Tt + EOS];
    sc[b] = s;
  }
}

// ---------------------------------------------------------------------------
// Combine: out = sum_b (partition[b] - score[b])
// ---------------------------------------------------------------------------
__global__ __launch_bounds__(128) void crf_combine(
    const float* __restrict__ part, const float* __restrict__ sc,
    float* __restrict__ out)
{
  __shared__ float s_red[2];
  const int tid = threadIdx.x;
  float v = part[tid] - sc[tid];
  #pragma unroll
  for (int o = 32; o > 0; o >>= 1) v += __shfl_xor(v, o);
  if ((tid & 63) == 0) s_red[tid >> 6] = v;
  __syncthreads();
  if (tid == 0) out[0] = s_red[0] + s_red[1];
}

extern "C" void kernel_launch(void* const* d_in, const int* in_sizes, int n_in,
                              void* d_out, int out_size, void* d_ws, size_t ws_size,
                              hipStream_t stream)
{
  const float* em    = (const float*)d_in[0];
  const float* trans = (const float*)d_in[1];
  const float* mask  = (const float*)d_in[2];
  const int*   tags  = (const int*)d_in[3];
  float* out = (float*)d_out;
  float* wsf = (float*)d_ws;
  float* part = wsf;          // [128]
  float* sc   = wsf + 128;    // [128]

  hipLaunchKernelGGL(crf_score, dim3(Bb), dim3(256), 0, stream,
                     em, trans, mask, tags, sc);
  hipLaunchKernelGGL(crf_forward, dim3(Bb), dim3(64), 0, stream,
                     em, trans, mask, part);
  hipLaunchKernelGGL(crf_combine, dim3(1), dim3(128), 0, stream,
                     part, sc, out);
}

// Round 4
// 556.671 us; speedup vs baseline: 2.9139x; 2.9139x over previous
//
#include <hip/hip_runtime.h>
#include <cmath>
#include <stdint.h>

#define SOS 0
#define EOS 1
#define Bb 128
#define Ss 1024
#define Tt 128
#define LOG2E 1.4426950408889634f
#define LN2f  0.6931471805599453f

typedef float  f32x2  __attribute__((ext_vector_type(2)));
typedef float  f32x4  __attribute__((ext_vector_type(4)));
typedef short  short4v __attribute__((ext_vector_type(4)));
typedef short  short8v __attribute__((ext_vector_type(8)));

// ws layout (floats)
#define WS_F    0        // fwd states [128][128]
#define WS_U    16384    // bwd states [128][128]
#define WS_CF   32768    // fwd log2-scales [128]
#define WS_CB   32896    // bwd log2-scales [128]
#define WS_PART 33024    // partition [128]
#define WS_SC   33152    // score [128]

__device__ __forceinline__ unsigned short f2bf(float f) {
  unsigned u = __float_as_uint(f);
  return (unsigned short)((u + 0x7FFFu + ((u >> 16) & 1u)) >> 16);
}
__device__ __forceinline__ float bf2f(unsigned short h) {
  return __uint_as_float(((unsigned)h) << 16);
}
// state-space column permutation: makes per-step w reads contiguous b64 pairs
__device__ __forceinline__ int sigma(int p) {
  int t = p >> 4, cc = p & 15;
  return 32 * (t & 3) + 2 * cc + (t >> 2);
}

// ---------------------------------------------------------------------------
// One recurrence step:  state' = (state ∘ w_it) · B      (B = M~ or M~^T)
// Single wave, no barriers. State lives in y_s (bf16, [p][m] rows of 16).
// PH = it mod 4 (static): measure max at PH0, fold rescale into w at PH1
// (produced for the PH3 consumer), account scale at PH3.
// ---------------------------------------------------------------------------
template<int PH>
__device__ __forceinline__ void crf_iter(
    int it, bool fwd, int b0, int c, int g, bool allones,
    const float* __restrict__ em, const float* __restrict__ mask,
    unsigned short* y_s, float (&w_lds)[4][4][136],
    const short8v (&Bf)[32],
    f32x4& emE0, f32x4& emE1, f32x4& emO0, f32x4& emO1,
    float& e_pend, f32x4& c4)
{
  constexpr int slot  = PH;             // it ≡ PH (mod 4) by construction
  constexpr int slot2 = (PH + 2) & 3;
  const unsigned ybase = (unsigned)(uintptr_t)y_s;

  // w for this step (written ≥2 iters ago; drained by intermediate waits)
  f32x2 wr[4][4];
#pragma unroll
  for (int m = 0; m < 4; ++m)
#pragma unroll
    for (int T = 0; T < 4; ++T)
      wr[m][T] = *(const f32x2*)&w_lds[slot][m][32 * T + 2 * c];

  // drain previous y-writes, then transpose-read A fragments
  asm volatile("s_waitcnt lgkmcnt(0)" ::: "memory");
  short4v t0[4], t1[4];
#pragma unroll
  for (int kt = 0; kt < 4; ++kt) {
    unsigned a1 = ybase + (unsigned)((32 * kt + 4 * g) * 32 + 2 * c);
    asm volatile("ds_read_b64_tr_b16 %0, %1" : "=v"(t0[kt]) : "v"(a1));
    asm volatile("ds_read_b64_tr_b16 %0, %1 offset:512" : "=v"(t1[kt]) : "v"(a1));
  }
  asm volatile("s_waitcnt lgkmcnt(0)" ::: "memory");
  __builtin_amdgcn_sched_barrier(0);

  short8v a8[4];
#pragma unroll
  for (int kt = 0; kt < 4; ++kt) {
    short8v v;
    v[0] = t0[kt][0]; v[1] = t0[kt][1]; v[2] = t0[kt][2]; v[3] = t0[kt][3];
    v[4] = t1[kt][0]; v[5] = t1[kt][1]; v[6] = t1[kt][2]; v[7] = t1[kt][3];
    a8[kt] = v;
  }

  f32x4 acc[8];
#pragma unroll
  for (int jt = 0; jt < 8; ++jt) acc[jt] = (f32x4){0.f, 0.f, 0.f, 0.f};
#pragma unroll
  for (int kt = 0; kt < 4; ++kt)
#pragma unroll
    for (int jt = 0; jt < 8; ++jt)
      acc[jt] = __builtin_amdgcn_mfma_f32_16x16x32_bf16(a8[kt], Bf[kt * 8 + jt], acc[jt], 0, 0, 0);

  // producer (off critical path): w for step it+2; reload em for step it+4
  {
    f32x4 ea, eb2;
    if constexpr (PH & 1) { ea = emO0; eb2 = emO1; } else { ea = emE0; eb2 = emE1; }
    const float fold = (PH == 1) ? e_pend : 0.0f;
    f32x4 wa, wb;
#pragma unroll
    for (int q = 0; q < 4; ++q) {
      wa[q] = __builtin_amdgcn_exp2f(fmaf(ea[q],  LOG2E, -fold));
      wb[q] = __builtin_amdgcn_exp2f(fmaf(eb2[q], LOG2E, -fold));
    }
    float* wp = &w_lds[slot2][g][8 * c];
    *(f32x4*)wp = wa;
    *(f32x4*)(wp + 4) = wb;
    const int lr = fwd ? it + 4 : 1023 - it - 4;
    const float* p = em + ((size_t)(b0 + g) * Ss + lr) * Tt + 8 * c;
    f32x4 n0 = *(const f32x4*)p;
    f32x4 n1 = *(const f32x4*)(p + 4);
    if constexpr (PH & 1) { emO0 = n0; emO1 = n1; } else { emE0 = n0; emE1 = n1; }
  }

  // y = acc * w (+ mask select), pack bf16, store new state
  float mloc = 0.0f;
  f32x4 m4 = (f32x4){1.f, 1.f, 1.f, 1.f};
  if (!allones) {
    const int wrow = fwd ? it : 1023 - it;
    m4[0] = mask[(size_t)(b0 + 0) * Ss + wrow];
    m4[1] = mask[(size_t)(b0 + 1) * Ss + wrow];
    m4[2] = mask[(size_t)(b0 + 2) * Ss + wrow];
    m4[3] = mask[(size_t)(b0 + 3) * Ss + wrow];
  }
#pragma unroll
  for (int jt = 0; jt < 8; ++jt) {
    const int T = jt & 3, hi = jt >> 2;
    float y0 = acc[jt][0] * wr[0][T][hi];
    float y1 = acc[jt][1] * wr[1][T][hi];
    float y2 = acc[jt][2] * wr[2][T][hi];
    float y3 = acc[jt][3] * wr[3][T][hi];
    if (!allones) {
      short4v ov = *(short4v*)&y_s[(16 * jt + c) * 16];
      if (m4[0] == 0.f) y0 = bf2f((unsigned short)ov[0]);
      if (m4[1] == 0.f) y1 = bf2f((unsigned short)ov[1]);
      if (m4[2] == 0.f) y2 = bf2f((unsigned short)ov[2]);
      if (m4[3] == 0.f) y3 = bf2f((unsigned short)ov[3]);
    }
    if constexpr (PH == 0)
      mloc = fmaxf(fmaxf(fmaxf(mloc, y0), fmaxf(y1, y2)), y3);
    if (g == 0) {
      short4v pk;
      pk[0] = (short)f2bf(y0); pk[1] = (short)f2bf(y1);
      pk[2] = (short)f2bf(y2); pk[3] = (short)f2bf(y3);
      *(short4v*)&y_s[(16 * jt + c) * 16] = pk;
    }
  }
  if constexpr (PH == 0) {
#pragma unroll
    for (int o = 1; o < 16; o <<= 1) mloc = fmaxf(mloc, __shfl_xor(mloc, o));
    float g0 = __shfl(mloc, c);   // group-0's reduced max
    int ei = (int)((__float_as_uint(g0) >> 23) & 255u) - 127;
    e_pend = (float)ei;
  }
  if constexpr (PH == 3) {
    if (allones) {
      c4[0] += e_pend; c4[1] += e_pend; c4[2] += e_pend; c4[3] += e_pend;
    } else {
      c4[0] += (m4[0] != 0.f) ? e_pend : 0.f;
      c4[1] += (m4[1] != 0.f) ? e_pend : 0.f;
      c4[2] += (m4[2] != 0.f) ? e_pend : 0.f;
      c4[3] += (m4[3] != 0.f) ? e_pend : 0.f;
    }
  }
}

// ---------------------------------------------------------------------------
// Forward/backward half-chains. 64 blocks x 1 wave: blocks 0-31 forward
// (4 chains each), 32-63 backward. No barriers anywhere in the main loop.
// ---------------------------------------------------------------------------
__global__ __launch_bounds__(64) void crf_fb(
    const float* __restrict__ em, const float* __restrict__ trans,
    const float* __restrict__ mask, float* __restrict__ wsf)
{
  __shared__ __align__(16) float s_trans[Tt * Tt];
  __shared__ __align__(16) unsigned short y_s[128 * 16];
  __shared__ __align__(16) float w_lds[4][4][136];

  const int l = threadIdx.x, c = l & 15, g = l >> 4;
  const int bk = blockIdx.x;
  const bool fwd = bk < 32;
  const int b0 = (fwd ? bk : bk - 32) * 4;
  const unsigned ybase = (unsigned)(uintptr_t)y_s;

  // stage transition matrix
  for (int itr = 0; itr < 64; ++itr)
    ((f32x4*)s_trans)[itr * 64 + l] = ((const f32x4*)trans)[itr * 64 + l];

  // Build B-fragments THROUGH the tr-read path (A/B k-order auto-consistent).
  short8v Bf[32];
#pragma unroll
  for (int jt = 0; jt < 8; ++jt) {
    asm volatile("s_waitcnt lgkmcnt(0)" ::: "memory");
#pragma unroll
    for (int rr = 0; rr < 2; ++rr) {
      const int k = l + rr * 64;
#pragma unroll
      for (int nn4 = 0; nn4 < 4; ++nn4) {
        short4v pk;
#pragma unroll
        for (int q = 0; q < 4; ++q) {
          const int nn = nn4 * 4 + q, n = 16 * jt + nn;
          const int ia = fwd ? sigma(k) : sigma(n);
          const int ib = fwd ? sigma(n) : sigma(k);
          pk[q] = (short)f2bf(__builtin_amdgcn_exp2f(s_trans[ia * Tt + ib] * LOG2E));
        }
        *(short4v*)&y_s[k * 16 + nn4 * 4] = pk;
      }
    }
    asm volatile("s_waitcnt lgkmcnt(0)" ::: "memory");
#pragma unroll
    for (int kt = 0; kt < 4; ++kt) {
      unsigned a1 = ybase + (unsigned)((32 * kt + 4 * g) * 32 + 2 * c);
      short4v u0, u1;
      asm volatile("ds_read_b64_tr_b16 %0, %1" : "=v"(u0) : "v"(a1));
      asm volatile("ds_read_b64_tr_b16 %0, %1 offset:512" : "=v"(u1) : "v"(a1));
      asm volatile("s_waitcnt lgkmcnt(0)" ::: "memory");
      short8v v;
      v[0] = u0[0]; v[1] = u0[1]; v[2] = u0[2]; v[3] = u0[3];
      v[4] = u1[0]; v[5] = u1[1]; v[6] = u1[2]; v[7] = u1[3];
      Bf[kt * 8 + jt] = v;
    }
  }

  // zero state buffer (rows m>=4 must stay 0 forever)
  {
    short4v z = (short4v){0, 0, 0, 0};
#pragma unroll
    for (int rr = 0; rr < 2; ++rr) {
      const int k = l + rr * 64;
#pragma unroll
      for (int nn4 = 0; nn4 < 4; ++nn4) *(short4v*)&y_s[k * 16 + nn4 * 4] = z;
    }
  }

  // initial state: fwd f0 = exp(trans[SOS,:]+em[:,0,:]);  bwd v = exp(trans[:,EOS])
  if (g == 0) {
#pragma unroll
    for (int t = 0; t < 8; ++t) {
      const int p = 16 * t + c, j = sigma(p);
      short4v pk;
#pragma unroll
      for (int m = 0; m < 4; ++m) {
        float x;
        if (fwd) x = (s_trans[SOS * Tt + j] + em[((size_t)(b0 + m) * Ss) * Tt + j]) * LOG2E;
        else     x = s_trans[j * Tt + EOS] * LOG2E;
        pk[m] = (short)f2bf(__builtin_amdgcn_exp2f(x));
      }
      *(short4v*)&y_s[p * 16] = pk;
    }
  }

  // mask fast-path check
  float mn = 1.0f;
  for (int r = 0; r < 4; ++r)
    for (int idx = l; idx < Ss; idx += 64)
      mn = fminf(mn, mask[(size_t)(b0 + r) * Ss + idx]);
#pragma unroll
  for (int o = 1; o < 64; o <<= 1) mn = fminf(mn, __shfl_xor(mn, o));
  const bool allones = (mn == 1.0f);

  // w prologue (iters i0, i0+1) + em preload (iters i0+2, i0+3)
  const int i0 = fwd ? 1 : 0;
#pragma unroll
  for (int s = 0; s < 2; ++s) {
    const int itw = i0 + s;
    const int row = fwd ? itw : 1023 - itw;
    const int sl = itw & 3;
    const float* p = em + ((size_t)(b0 + g) * Ss + row) * Tt + 8 * c;
    f32x4 a = *(const f32x4*)p, b = *(const f32x4*)(p + 4);
    f32x4 wa, wb;
#pragma unroll
    for (int q = 0; q < 4; ++q) {
      wa[q] = __builtin_amdgcn_exp2f(a[q] * LOG2E);
      wb[q] = __builtin_amdgcn_exp2f(b[q] * LOG2E);
    }
    float* wp = &w_lds[sl][g][8 * c];
    *(f32x4*)wp = wa; *(f32x4*)(wp + 4) = wb;
  }
  f32x4 emE0, emE1, emO0, emO1;
  {
    const int itA = i0 + 2, itB = i0 + 3;
    const int rowA = fwd ? itA : 1023 - itA;
    const int rowB = fwd ? itB : 1023 - itB;
    const float* pA = em + ((size_t)(b0 + g) * Ss + rowA) * Tt + 8 * c;
    const float* pB = em + ((size_t)(b0 + g) * Ss + rowB) * Tt + 8 * c;
    if ((itA & 1) == 0) {
      emE0 = *(const f32x4*)pA; emE1 = *(const f32x4*)(pA + 4);
      emO0 = *(const f32x4*)pB; emO1 = *(const f32x4*)(pB + 4);
    } else {
      emO0 = *(const f32x4*)pA; emO1 = *(const f32x4*)(pA + 4);
      emE0 = *(const f32x4*)pB; emE1 = *(const f32x4*)(pB + 4);
    }
  }

  float e_pend = 0.f;
  f32x4 c4 = (f32x4){0.f, 0.f, 0.f, 0.f};

#define ARGS fwd, b0, c, g, allones, em, mask, y_s, w_lds, Bf, emE0, emE1, emO0, emO1, e_pend, c4
  if (fwd) {
    int i = 1;
    for (int blk = 0; blk < 127; ++blk) {
      crf_iter<1>(i, ARGS); crf_iter<2>(i + 1, ARGS);
      crf_iter<3>(i + 2, ARGS); crf_iter<0>(i + 3, ARGS);
      i += 4;
    }
    crf_iter<1>(509, ARGS); crf_iter<2>(510, ARGS); crf_iter<3>(511, ARGS);
  } else {
    int n = 0;
    for (int blk = 0; blk < 128; ++blk) {
      crf_iter<0>(n, ARGS); crf_iter<1>(n + 1, ARGS);
      crf_iter<2>(n + 2, ARGS); crf_iter<3>(n + 3, ARGS);
      n += 4;
    }
  }
#undef ARGS

  // dump final state (tilde index space, consistent between fwd/bwd) + scales
  asm volatile("s_waitcnt lgkmcnt(0)" ::: "memory");
  const int so = fwd ? WS_F : WS_U;
#pragma unroll
  for (int rr = 0; rr < 2; ++rr) {
    const int p = l + rr * 64;
    short4v v = *(short4v*)&y_s[p * 16];
#pragma unroll
    for (int m = 0; m < 4; ++m)
      wsf[so + (b0 + m) * 128 + p] = bf2f((unsigned short)v[m]);
  }
  if (l == 0) {
    float* cp = wsf + (fwd ? WS_CF : WS_CB);
    cp[b0 + 0] = c4[0]; cp[b0 + 1] = c4[1];
    cp[b0 + 2] = c4[2]; cp[b0 + 3] = c4[3];
  }
}

// ---------------------------------------------------------------------------
// partition[b] = ln( f_511 . u_511 ) + (cf+cb)*ln2
// ---------------------------------------------------------------------------
__global__ __launch_bounds__(64) void crf_combine1(float* __restrict__ wsf)
{
  const int b = blockIdx.x, l = threadIdx.x;
  float a = wsf[WS_F + b * 128 + l]      * wsf[WS_U + b * 128 + l]
          + wsf[WS_F + b * 128 + 64 + l] * wsf[WS_U + b * 128 + 64 + l];
#pragma unroll
  for (int o = 32; o > 0; o >>= 1) a += __shfl_xor(a, o);
  if (l == 0)
    wsf[WS_PART + b] = (log2f(a) + wsf[WS_CF + b] + wsf[WS_CB + b]) * LN2f;
}

// ---------------------------------------------------------------------------
// Score (numerator): one block per batch element, gather + reduce.
// ---------------------------------------------------------------------------
__global__ __launch_bounds__(256) void crf_score(
    const float* __restrict__ em, const float* __restrict__ trans,
    const float* __restrict__ mask, const int* __restrict__ tags,
    float* __restrict__ sc)
{
  __shared__ float s_red[4];
  __shared__ float s_red2[4];
  const int tid = threadIdx.x;
  const int b = blockIdx.x;
  const size_t em_base = (size_t)b * Ss * Tt;
  const int* tg = tags + b * Ss;
  const float* mk = mask + b * Ss;

  float part = 0.f, msum = 0.f;
  for (int i = tid; i < Ss; i += 256) {
    float m = mk[i];
    msum += m;
    if (i >= 1) {
      int tc = tg[i], tp = tg[i - 1];
      part += m * (em[em_base + (size_t)i * Tt + tc] + trans[tp * Tt + tc]);
    }
  }
#pragma unroll
  for (int o = 32; o > 0; o >>= 1) {
    part += __shfl_xor(part, o);
    msum += __shfl_xor(msum, o);
  }
  if ((tid & 63) == 0) { s_red[tid >> 6] = part; s_red2[tid >> 6] = msum; }
  __syncthreads();
  if (tid == 0) {
    float p  = s_red[0] + s_red[1] + s_red[2] + s_red[3];
    float ms = s_red2[0] + s_red2[1] + s_red2[2] + s_red2[3];
    int last = (int)(ms + 0.5f) - 1;
    int t0 = tg[0];
    float s = trans[SOS * Tt + t0] + em[em_base + t0] + p
            + trans[tg[last] * Tt + EOS];
    sc[b] = s;
  }
}

// ---------------------------------------------------------------------------
// out = sum_b (partition[b] - score[b])
// ---------------------------------------------------------------------------
__global__ __launch_bounds__(128) void crf_final(
    const float* __restrict__ wsf, float* __restrict__ out)
{
  __shared__ float s_red[2];
  const int tid = threadIdx.x;
  float v = wsf[WS_PART + tid] - wsf[WS_SC + tid];
#pragma unroll
  for (int o = 32; o > 0; o >>= 1) v += __shfl_xor(v, o);
  if ((tid & 63) == 0) s_red[tid >> 6] = v;
  __syncthreads();
  if (tid == 0) out[0] = s_red[0] + s_red[1];
}

extern "C" void kernel_launch(void* const* d_in, const int* in_sizes, int n_in,
                              void* d_out, int out_size, void* d_ws, size_t ws_size,
                              hipStream_t stream)
{
  const float* em    = (const float*)d_in[0];
  const float* trans = (const float*)d_in[1];
  const float* mask  = (const float*)d_in[2];
  const int*   tags  = (const int*)d_in[3];
  float* out = (float*)d_out;
  float* wsf = (float*)d_ws;

  hipLaunchKernelGGL(crf_score, dim3(Bb), dim3(256), 0, stream,
                     em, trans, mask, tags, wsf + WS_SC);
  hipLaunchKernelGGL(crf_fb, dim3(64), dim3(64), 0, stream,
                     em, trans, mask, wsf);
  hipLaunchKernelGGL(crf_combine1, dim3(Bb), dim3(64), 0, stream, wsf);
  hipLaunchKernelGGL(crf_final, dim3(1), dim3(128), 0, stream, wsf, out);
}